// Round 10
// baseline (5638.845 us; speedup 1.0000x reference)
//
#include <hip/hip_runtime.h>
#include <hip/hip_bf16.h>

#define NQ 8
#define NC 1024
#define ND 512
#define NROWTOT 32768
#define QOFF 16777216ULL

typedef short short8 __attribute__((ext_vector_type(8)));
typedef float f32x16 __attribute__((ext_vector_type(16)));

__device__ __forceinline__ unsigned f2bf_u(float f) {
  unsigned u = __float_as_uint(f);
  return (u + 0x7FFFu + ((u >> 16) & 1u)) >> 16;
}
__device__ __forceinline__ void merge_in(float &d1, int &i1, float &d2, int &i2,
                                         float nd, int ni) {
  bool b1 = (nd < d1) || (nd == d1 && ni < i1);
  bool b2 = (nd < d2) || (nd == d2 && ni < i2);
  if (b1) { d2 = d1; i2 = i1; d1 = nd; i1 = ni; }
  else if (b2) { d2 = nd; i2 = ni; }
}

__global__ __launch_bounds__(256) void cbsq_kernel(const float* __restrict__ cbg,
                                                   float* __restrict__ ws) {
  const int tid = threadIdx.x, wv = tid >> 6, lane = tid & 63;
  const int cbase = blockIdx.x * 32 + wv * 8;
  for (int j = 0; j < 8; ++j) {
    const int c = cbase + j;
    const float4* p = reinterpret_cast<const float4*>(cbg + (size_t)c * ND + lane * 8);
    float4 a = p[0], b = p[1];
    float s = a.x*a.x + a.y*a.y + a.z*a.z + a.w*a.w
            + b.x*b.x + b.y*b.y + b.z*b.z + b.w*b.w;
    #pragma unroll
    for (int m = 1; m < 64; m <<= 1) s += __shfl_xor(s, m, 64);
    if (lane == 0) ws[c] = s;
  }
}

// Split codebooks into MFMA-B-frag-ordered bf16 hi/lo.
// chunk = (q*2+cp)*32+ks ; within chunk: [phys16][8k] bf16,
// i16 = grp*512 + col (grp = k-half of kstep), phys16 = i16 ^ ((i16>>3)&7)
__global__ __launch_bounds__(256) void fmt_kernel(const float* __restrict__ cbg,
                                                  unsigned short* __restrict__ Bh,
                                                  unsigned short* __restrict__ Bl) {
  int t = blockIdx.x * 256 + threadIdx.x;   // 524288 total
  int i16 = t & 1023, ks = (t >> 10) & 31, cp = (t >> 15) & 1, q = (t >> 16) & 7;
  int grp = i16 >> 9, col = i16 & 511, c = cp * 512 + col;
  const float* src = cbg + ((size_t)q * NC + c) * ND + ks * 16 + grp * 8;
  float4 a = reinterpret_cast<const float4*>(src)[0];
  float4 b = reinterpret_cast<const float4*>(src)[1];
  float v[8] = {a.x, a.y, a.z, a.w, b.x, b.y, b.z, b.w};
  unsigned short hv[8], lv[8];
  #pragma unroll
  for (int j = 0; j < 8; ++j) {
    unsigned hb = f2bf_u(v[j]);
    float hf = __uint_as_float(hb << 16);
    unsigned lb = f2bf_u(v[j] - hf);
    hv[j] = (unsigned short)hb; lv[j] = (unsigned short)lb;
  }
  int phys = i16 ^ ((i16 >> 3) & 7);
  size_t dst = (size_t)(t >> 10) * 8192 + (size_t)phys * 8;
  uint4 wh, wl;
  wh.x = hv[0] | ((unsigned)hv[1] << 16); wh.y = hv[2] | ((unsigned)hv[3] << 16);
  wh.z = hv[4] | ((unsigned)hv[5] << 16); wh.w = hv[6] | ((unsigned)hv[7] << 16);
  wl.x = lv[0] | ((unsigned)lv[1] << 16); wl.y = lv[2] | ((unsigned)lv[3] << 16);
  wl.z = lv[4] | ((unsigned)lv[5] << 16); wl.w = lv[6] | ((unsigned)lv[7] << 16);
  *reinterpret_cast<uint4*>(Bh + dst) = wh;
  *reinterpret_cast<uint4*>(Bl + dst) = wl;
}

#define ROWS32 32
#define RSTRIDE 260
#define TAU2 0.02f

__device__ __forceinline__ int chunk_of(int n, int cpswap, int phase) {
  int qn = n >> 6, cpin = (n >> 5) & 1, ksn = n & 31;
  return ((qn * 2 + (cpin ^ cpswap)) * 32) + ((ksn + phase) & 31);
}

// 512 threads = 8 waves, 32 rows/block, 1024 blocks.
// B staged via global_load_lds double-buffer (32 KB/chunk), 1 barrier/k-step.
// Per wave per k-step: 4 global_load_lds + 6 ds_read_b128 + 6 MFMA.
__global__ __launch_bounds__(512, 2) void rvq_mfma(
    const float* __restrict__ emb, const float* __restrict__ cbg,
    const float* __restrict__ cbsq_g, float* __restrict__ lossws,
    const unsigned short* __restrict__ Bh, const unsigned short* __restrict__ Bl,
    float* __restrict__ outf) {
  __shared__ unsigned resH[ROWS32 * RSTRIDE];   // 33.3 KB
  __shared__ unsigned resL[ROWS32 * RSTRIDE];   // 33.3 KB
  __shared__ uint4 Bbuf[2][2048];               // 64 KB: per buf 16K hi + 16K lo
  __shared__ float mrgd[2][8][ROWS32][2];
  __shared__ int   mrgi[2][8][ROWS32][2];
  __shared__ int   idx_all[NQ][ROWS32];
  __shared__ int   fi_sh[ROWS32];
  __shared__ int   tlist[ROWS32][3];
  __shared__ int   tcount;
  __shared__ float wred[8];

  const int tid = threadIdx.x;
  const int w = tid >> 6, l = tid & 63;
  const int n0 = blockIdx.x * ROWS32;
  const int colq = w * 64;                    // 8 colgroups of 64 cols
  const int arow = l & 31;
  const int phase = blockIdx.x & 31;
  const int cpswap = (blockIdx.x >> 5) & 1;

  union U8 { uint4 q4; short8 s; };

  const int row = tid & 31, seg = tid >> 5;   // 16 segs x 32 dims
  const int kb0i = seg * 16;                  // dword offset (2 k per dword)

  { // init: emb -> hi/lo bf16x2 packed, MFMA-operand order
    const float4* src = reinterpret_cast<const float4*>(emb + (size_t)(n0 + row) * ND + seg * 32);
    float4 v8[8];
    #pragma unroll
    for (int i = 0; i < 8; ++i) v8[i] = src[i];
    #pragma unroll
    for (int j = 0; j < 4; ++j) {
      float vv[8];
      vv[0]=v8[2*j].x; vv[1]=v8[2*j].y; vv[2]=v8[2*j].z; vv[3]=v8[2*j].w;
      vv[4]=v8[2*j+1].x; vv[5]=v8[2*j+1].y; vv[6]=v8[2*j+1].z; vv[7]=v8[2*j+1].w;
      unsigned hh[8], ll[8];
      #pragma unroll
      for (int e = 0; e < 8; ++e) {
        hh[e] = f2bf_u(vv[e]);
        ll[e] = f2bf_u(vv[e] - __uint_as_float(hh[e] << 16));
      }
      uint4 H, L;
      H.x = hh[0] | (hh[1] << 16); H.y = hh[2] | (hh[3] << 16);
      H.z = hh[4] | (hh[5] << 16); H.w = hh[6] | (hh[7] << 16);
      L.x = ll[0] | (ll[1] << 16); L.y = ll[2] | (ll[3] << 16);
      L.z = ll[4] | (ll[5] << 16); L.w = ll[6] | (ll[7] << 16);
      const int off = row * RSTRIDE + kb0i + 4 * j;
      *reinterpret_cast<uint4*>(&resH[off]) = H;
      *reinterpret_cast<uint4*>(&resL[off]) = L;
    }
  }

  int bb[2];  // byte offsets of this lane's B granules within a 16 KB half-chunk
  #pragma unroll
  for (int t = 0; t < 2; ++t) {
    int i16 = ((l >> 5) << 9) + colq + t * 32 + (l & 31);
    bb[t] = (i16 ^ ((i16 >> 3) & 7)) * 16;
  }
  const int kbh = (l >> 5) * 4;
  const int abase = arow * RSTRIDE;

#define STAGE(c, b) { \
    const char* _hs = (const char*)(Bh + (size_t)(c) * 8192) + (w << 11) + (l << 4); \
    const char* _ls = (const char*)(Bl + (size_t)(c) * 8192) + (w << 11) + (l << 4); \
    char* _ld = (char*)&Bbuf[(b)][0] + (w << 11); \
    __builtin_amdgcn_global_load_lds((const __attribute__((address_space(1))) void*)_hs, \
        (__attribute__((address_space(3))) void*)_ld, 16, 0, 0); \
    __builtin_amdgcn_global_load_lds((const __attribute__((address_space(1))) void*)(_hs + 1024), \
        (__attribute__((address_space(3))) void*)(_ld + 1024), 16, 0, 0); \
    __builtin_amdgcn_global_load_lds((const __attribute__((address_space(1))) void*)_ls, \
        (__attribute__((address_space(3))) void*)(_ld + 16384), 16, 0, 0); \
    __builtin_amdgcn_global_load_lds((const __attribute__((address_space(1))) void*)(_ls + 1024), \
        (__attribute__((address_space(3))) void*)(_ld + 17408), 16, 0, 0); \
  }

  STAGE(chunk_of(0, cpswap, phase), 0);
  __syncthreads();

  for (int q = 0; q < NQ; ++q) {
    if (tid == 0) tcount = 0;   // ordered before merge atomics by k-loop barriers

    #pragma unroll 1
    for (int cpi = 0; cpi < 2; ++cpi) {
      const int cp = cpi ^ cpswap;
      f32x16 acc[2];
      #pragma unroll
      for (int t = 0; t < 2; ++t)
        #pragma unroll
        for (int e = 0; e < 16; ++e) acc[t][e] = 0.f;

      float sqv[2];
      #pragma unroll
      for (int t = 0; t < 2; ++t)
        sqv[t] = cbsq_g[q * NC + cp * 512 + colq + t * 32 + (l & 31)];

      #pragma unroll 1
      for (int ksi = 0; ksi < 32; ++ksi) {
        const int n = q * 64 + cpi * 32 + ksi;
        if (n + 1 < 512) STAGE(chunk_of(n + 1, cpswap, phase), (n + 1) & 1);

        const int kk = (ksi + phase) & 31;
        const int a = abase + kk * 8 + kbh;
        U8 Ah, Al;
        Ah.q4 = *reinterpret_cast<const uint4*>(&resH[a]);
        Al.q4 = *reinterpret_cast<const uint4*>(&resL[a]);

        const char* bp = (const char*)&Bbuf[n & 1][0];
        U8 B0h, B1h, B0l, B1l;
        B0h.q4 = *reinterpret_cast<const uint4*>(bp + bb[0]);
        B1h.q4 = *reinterpret_cast<const uint4*>(bp + bb[1]);
        B0l.q4 = *reinterpret_cast<const uint4*>(bp + 16384 + bb[0]);
        B1l.q4 = *reinterpret_cast<const uint4*>(bp + 16384 + bb[1]);

        acc[0] = __builtin_amdgcn_mfma_f32_32x32x16_bf16(Ah.s, B0h.s, acc[0], 0, 0, 0);
        acc[0] = __builtin_amdgcn_mfma_f32_32x32x16_bf16(Al.s, B0h.s, acc[0], 0, 0, 0);
        acc[0] = __builtin_amdgcn_mfma_f32_32x32x16_bf16(Ah.s, B0l.s, acc[0], 0, 0, 0);
        acc[1] = __builtin_amdgcn_mfma_f32_32x32x16_bf16(Ah.s, B1h.s, acc[1], 0, 0, 0);
        acc[1] = __builtin_amdgcn_mfma_f32_32x32x16_bf16(Al.s, B1h.s, acc[1], 0, 0, 0);
        acc[1] = __builtin_amdgcn_mfma_f32_32x32x16_bf16(Ah.s, B1l.s, acc[1], 0, 0, 0);
        __syncthreads();
      }

      // epilogue: per-row top-2 across this wave's 64 cols
      #pragma unroll
      for (int rg2 = 0; rg2 < 16; ++rg2) {
        float d1 = INFINITY, d2 = INFINITY; int i1 = 0x7fffffff, i2 = 0x7fffffff;
        #pragma unroll
        for (int t = 0; t < 2; ++t) {
          int col = cp * 512 + colq + t * 32 + (l & 31);
          float dd = sqv[t] - 2.0f * acc[t][rg2];
          merge_in(d1, i1, d2, i2, dd, col);
        }
        #pragma unroll
        for (int m = 1; m < 32; m <<= 1) {
          float od1 = __shfl_xor(d1, m, 64), od2 = __shfl_xor(d2, m, 64);
          int oi1 = __shfl_xor(i1, m, 64), oi2 = __shfl_xor(i2, m, 64);
          merge_in(d1, i1, d2, i2, od1, oi1);
          merge_in(d1, i1, d2, i2, od2, oi2);
        }
        if ((l & 31) == 0) {
          int h = l >> 5;
          int rr = (rg2 & 3) + 8 * (rg2 >> 2) + 4 * h;
          mrgd[cp][w][rr][0] = d1; mrgd[cp][w][rr][1] = d2;
          mrgi[cp][w][rr][0] = i1; mrgi[cp][w][rr][1] = i2;
        }
      }
    }
    __syncthreads();

    // per-row merge of 2cp x 8 colgroups x top2 + trigger list
    if (tid < ROWS32) {
      float d1 = INFINITY, d2 = INFINITY; int i1 = 0x7fffffff, i2 = 0x7fffffff;
      #pragma unroll
      for (int c2 = 0; c2 < 2; ++c2)
        #pragma unroll
        for (int s2 = 0; s2 < 8; ++s2) {
          merge_in(d1, i1, d2, i2, mrgd[c2][s2][tid][0], mrgi[c2][s2][tid][0]);
          merge_in(d1, i1, d2, i2, mrgd[c2][s2][tid][1], mrgi[c2][s2][tid][1]);
        }
      int fi = i1 < 0 ? 0 : (i1 > NC - 1 ? NC - 1 : i1);
      int ib = i2 < 0 ? 0 : (i2 > NC - 1 ? NC - 1 : i2);
      fi_sh[tid] = fi;
      if (d2 - d1 < TAU2 && ib != fi) {
        int p = atomicAdd(&tcount, 1);
        tlist[p][0] = tid; tlist[p][1] = fi; tlist[p][2] = ib;
      }
    }
    __syncthreads();

    // cooperative exact rescore (stepped-fp32 residual, fp64 dists)
    {
      int nt_ = tcount;
      for (int it = w; it < nt_; it += 8) {
        int rr = tlist[it][0], ia = tlist[it][1], ib = tlist[it][2];
        float rv[8];
        const float4* ep = reinterpret_cast<const float4*>(emb + (size_t)(n0 + rr) * ND + l * 8);
        float4 e0 = ep[0], e1 = ep[1];
        rv[0]=e0.x; rv[1]=e0.y; rv[2]=e0.z; rv[3]=e0.w;
        rv[4]=e1.x; rv[5]=e1.y; rv[6]=e1.z; rv[7]=e1.w;
        for (int t2 = 0; t2 < q; ++t2) {
          const float4* cr = reinterpret_cast<const float4*>(
              cbg + ((size_t)t2 * NC + idx_all[t2][rr]) * ND + l * 8);
          float4 c0 = cr[0], c1 = cr[1];
          rv[0]-=c0.x; rv[1]-=c0.y; rv[2]-=c0.z; rv[3]-=c0.w;
          rv[4]-=c1.x; rv[5]-=c1.y; rv[6]-=c1.z; rv[7]-=c1.w;
        }
        double da = 0.0, db = 0.0;
        {
          const float4* cr = reinterpret_cast<const float4*>(
              cbg + ((size_t)q * NC + ia) * ND + l * 8);
          float4 c0 = cr[0], c1 = cr[1];
          float cv[8] = {c0.x,c0.y,c0.z,c0.w,c1.x,c1.y,c1.z,c1.w};
          #pragma unroll
          for (int j = 0; j < 8; ++j) { double e = (double)cv[j] - (double)rv[j]; da += e * e; }
        }
        {
          const float4* cr = reinterpret_cast<const float4*>(
              cbg + ((size_t)q * NC + ib) * ND + l * 8);
          float4 c0 = cr[0], c1 = cr[1];
          float cv[8] = {c0.x,c0.y,c0.z,c0.w,c1.x,c1.y,c1.z,c1.w};
          #pragma unroll
          for (int j = 0; j < 8; ++j) { double e = (double)cv[j] - (double)rv[j]; db += e * e; }
        }
        #pragma unroll
        for (int m = 1; m < 64; m <<= 1) { da += __shfl_xor(da, m, 64); db += __shfl_xor(db, m, 64); }
        if (l == 0 && (db < da || (db == da && ib < ia))) fi_sh[rr] = ib;
      }
    }
    __syncthreads();

    if (tid < ROWS32) {
      idx_all[q][tid] = fi_sh[tid];
      outf[QOFF + (size_t)(n0 + tid) * NQ + q] = (float)fi_sh[tid];
    }

    // residual update + loss (+ fused quantized at last stage); 16 threads/row
    {
      const float* crow = cbg + ((size_t)q * NC + fi_sh[row]) * ND;
      const float4* cp4 = reinterpret_cast<const float4*>(crow + seg * 32);
      const float4* ep4 = reinterpret_cast<const float4*>(emb + (size_t)(n0 + row) * ND + seg * 32);
      float4* op4 = reinterpret_cast<float4*>(outf + (size_t)(n0 + row) * ND + seg * 32);
      float4 cv8[8];
      #pragma unroll
      for (int u2 = 0; u2 < 8; ++u2) cv8[u2] = cp4[u2];
      float ls = 0.f;
      #pragma unroll
      for (int j = 0; j < 4; ++j) {
        const int off = row * RSTRIDE + kb0i + 4 * j;
        uint4 H = *reinterpret_cast<const uint4*>(&resH[off]);
        uint4 L = *reinterpret_cast<const uint4*>(&resL[off]);
        unsigned hu[4] = {H.x, H.y, H.z, H.w};
        unsigned lu[4] = {L.x, L.y, L.z, L.w};
        float cf[8];
        cf[0]=cv8[2*j].x; cf[1]=cv8[2*j].y; cf[2]=cv8[2*j].z; cf[3]=cv8[2*j].w;
        cf[4]=cv8[2*j+1].x; cf[5]=cv8[2*j+1].y; cf[6]=cv8[2*j+1].z; cf[7]=cv8[2*j+1].w;
        float x[8];
        #pragma unroll
        for (int e = 0; e < 4; ++e) {
          float rlo = __uint_as_float(hu[e] << 16) + __uint_as_float(lu[e] << 16);
          float rhi = __uint_as_float(hu[e] & 0xFFFF0000u) + __uint_as_float(lu[e] & 0xFFFF0000u);
          x[2*e]   = rlo - cf[2*e];
          x[2*e+1] = rhi - cf[2*e+1];
        }
        unsigned nh[4], nl[4];
        #pragma unroll
        for (int e = 0; e < 4; ++e) {
          unsigned h0 = f2bf_u(x[2*e]);
          unsigned l0 = f2bf_u(x[2*e] - __uint_as_float(h0 << 16));
          unsigned h1 = f2bf_u(x[2*e+1]);
          unsigned l1 = f2bf_u(x[2*e+1] - __uint_as_float(h1 << 16));
          nh[e] = h0 | (h1 << 16);
          nl[e] = l0 | (l1 << 16);
          ls += x[2*e] * x[2*e] + x[2*e+1] * x[2*e+1];
        }
        uint4 NH, NL;
        NH.x = nh[0]; NH.y = nh[1]; NH.z = nh[2]; NH.w = nh[3];
        NL.x = nl[0]; NL.y = nl[1]; NL.z = nl[2]; NL.w = nl[3];
        *reinterpret_cast<uint4*>(&resH[off]) = NH;
        *reinterpret_cast<uint4*>(&resL[off]) = NL;
        if (q == NQ - 1) {
          float4 e0 = ep4[2*j], e1 = ep4[2*j+1];
          float4 q0, q1;
          q0.x = e0.x - x[0]; q0.y = e0.y - x[1]; q0.z = e0.z - x[2]; q0.w = e0.w - x[3];
          q1.x = e1.x - x[4]; q1.y = e1.y - x[5]; q1.z = e1.z - x[6]; q1.w = e1.w - x[7];
          op4[2*j] = q0; op4[2*j+1] = q1;
        }
      }
      #pragma unroll
      for (int m = 1; m < 64; m <<= 1) ls += __shfl_xor(ls, m, 64);
      if (l == 0) wred[w] = ls;
    }
    __syncthreads();
    if (tid == 0) {
      float s = 0.f;
      #pragma unroll
      for (int i = 0; i < 8; ++i) s += wred[i];
      lossws[blockIdx.x * NQ + q] = s;
    }
    __syncthreads();
  }
#undef STAGE
}

// ---------------- fallback (round-4 passing kernel) ----------------
#define ROWS 32
#define BK 32
#define CP 512
#define TAU 0.05f

__global__ __launch_bounds__(256, 1) void rvq_fb(
    const float* __restrict__ emb, const float* __restrict__ cbg,
    const float* __restrict__ cbsq, float* __restrict__ lossws,
    float* __restrict__ outf) {
  __shared__ float resT[ND][ROWS];
  __shared__ float cc[BK][CP];
  __shared__ int   idx_sh[ROWS];
  __shared__ float wred[4];

  const int tid = threadIdx.x;
  const int wv = tid >> 6, lane = tid & 63;
  const int rg = wv, cg = lane;
  const int n0 = blockIdx.x * ROWS;

  float qacc[64];
  #pragma unroll
  for (int s = 0; s < 64; ++s) qacc[s] = 0.f;

  {
    const int r = tid & 31, db = tid >> 5;
    const float4* src = reinterpret_cast<const float4*>(emb + (size_t)(n0 + r) * ND + db * 64);
    #pragma unroll
    for (int s = 0; s < 16; ++s) {
      float4 v = src[s];
      int d = db * 64 + s * 4;
      resT[d+0][r] = v.x; resT[d+1][r] = v.y; resT[d+2][r] = v.z; resT[d+3][r] = v.w;
    }
  }
  __syncthreads();

  const int c0l = cg * 8;
  const int swm = (c0l >> 6) << 2;
  const int off0 = c0l ^ swm;
  const int off1 = (c0l + 4) ^ swm;

  for (int q = 0; q < NQ; ++q) {
    const float* cbq = cbg + (size_t)q * NC * ND;
    float bd1[8], bd2[8]; int bi1[8], bi2[8];
    #pragma unroll
    for (int j = 0; j < 8; ++j) { bd1[j]=INFINITY; bd2[j]=INFINITY; bi1[j]=0x7fffffff; bi2[j]=0x7fffffff; }

    for (int cp = 0; cp < 2; ++cp) {
      float acc[8][8];
      #pragma unroll
      for (int a = 0; a < 8; ++a)
        #pragma unroll
        for (int b = 0; b < 8; ++b) acc[a][b] = 0.f;

      for (int kc = 0; kc < ND / BK; ++kc) {
        __syncthreads();
        {
          const int half = tid & 1;
          const int k0 = half * 16;
          #pragma unroll
          for (int it = 0; it < 4; ++it) {
            const int c = (tid >> 1) + it * 128;
            const int pc = c ^ ((c >> 6) << 2);
            const float4* src = reinterpret_cast<const float4*>(
                cbq + (size_t)(cp * CP + c) * ND + kc * BK + half * 16);
            float4 v0 = src[0], v1 = src[1], v2 = src[2], v3 = src[3];
            cc[k0+ 0][pc]=v0.x; cc[k0+ 1][pc]=v0.y; cc[k0+ 2][pc]=v0.z; cc[k0+ 3][pc]=v0.w;
            cc[k0+ 4][pc]=v1.x; cc[k0+ 5][pc]=v1.y; cc[k0+ 6][pc]=v1.z; cc[k0+ 7][pc]=v1.w;
            cc[k0+ 8][pc]=v2.x; cc[k0+ 9][pc]=v2.y; cc[k0+10][pc]=v2.z; cc[k0+11][pc]=v2.w;
            cc[k0+12][pc]=v3.x; cc[k0+13][pc]=v3.y; cc[k0+14][pc]=v3.z; cc[k0+15][pc]=v3.w;
          }
        }
        __syncthreads();

        float tmp[8][8];
        #pragma unroll
        for (int a = 0; a < 8; ++a)
          #pragma unroll
          for (int b = 0; b < 8; ++b) tmp[a][b] = 0.f;

        #pragma unroll
        for (int kk = 0; kk < BK; ++kk) {
          const float4* rp = reinterpret_cast<const float4*>(&resT[kc * BK + kk][rg * 8]);
          float4 r0 = rp[0], r1 = rp[1];
          const float* ccrow = &cc[kk][0];
          float4 c0 = *reinterpret_cast<const float4*>(ccrow + off0);
          float4 c1 = *reinterpret_cast<const float4*>(ccrow + off1);
          float rv[8] = {r0.x, r0.y, r0.z, r0.w, r1.x, r1.y, r1.z, r1.w};
          float cv[8] = {c0.x, c0.y, c0.z, c0.w, c1.x, c1.y, c1.z, c1.w};
          #pragma unroll
          for (int a = 0; a < 8; ++a)
            #pragma unroll
            for (int b = 0; b < 8; ++b)
              tmp[a][b] = fmaf(rv[a], cv[b], tmp[a][b]);
        }
        #pragma unroll
        for (int a = 0; a < 8; ++a)
          #pragma unroll
          for (int b = 0; b < 8; ++b) acc[a][b] += tmp[a][b];
      }

      const float4* qp = reinterpret_cast<const float4*>(cbsq + q * NC + cp * CP + cg * 8);
      float4 s0 = qp[0], s1 = qp[1];
      float sqv[8] = {s0.x, s0.y, s0.z, s0.w, s1.x, s1.y, s1.z, s1.w};
      #pragma unroll
      for (int r = 0; r < 8; ++r) {
        float d1 = INFINITY, d2 = INFINITY; int i1 = 0x7fffffff, i2 = 0x7fffffff;
        #pragma unroll
        for (int j = 0; j < 8; ++j) {
          float dd = sqv[j] - 2.0f * acc[r][j];
          merge_in(d1, i1, d2, i2, dd, cp * CP + cg * 8 + j);
        }
        #pragma unroll
        for (int m = 1; m < 64; m <<= 1) {
          float od1 = __shfl_xor(d1, m, 64), od2 = __shfl_xor(d2, m, 64);
          int oi1 = __shfl_xor(i1, m, 64), oi2 = __shfl_xor(i2, m, 64);
          merge_in(d1, i1, d2, i2, od1, oi1);
          merge_in(d1, i1, d2, i2, od2, oi2);
        }
        merge_in(bd1[r], bi1[r], bd2[r], bi2[r], d1, i1);
        merge_in(bd1[r], bi1[r], bd2[r], bi2[r], d2, i2);
      }
    }

    #pragma unroll 1
    for (int r = 0; r < 8; ++r) {
      int fi = bi1[r];
      if (bd2[r] - bd1[r] < TAU) {
        const int row = rg * 8 + r;
        const int ia = bi1[r], ib = bi2[r];
        double da = 0.0, db2 = 0.0;
        #pragma unroll 1
        for (int t = 0; t < 2; ++t) {
          const int cidx = t ? ib : ia;
          const float* cr = cbq + (size_t)cidx * ND;
          double dot = 0.0, ss = 0.0;
          #pragma unroll
          for (int u = 0; u < 8; ++u) {
            int k = lane * 8 + u;
            double cvv = (double)cr[k];
            double rvv = (double)resT[k][row];
            dot += cvv * rvv; ss += cvv * cvv;
          }
          #pragma unroll
          for (int m = 1; m < 64; m <<= 1) { dot += __shfl_xor(dot, m, 64); ss += __shfl_xor(ss, m, 64); }
          double dd = ss - 2.0 * dot;
          if (t) db2 = dd; else da = dd;
        }
        if (db2 < da || (db2 == da && ib < ia)) fi = ib;
      }
      fi = fi < 0 ? 0 : (fi > NC - 1 ? NC - 1 : fi);
      if (lane == 0) {
        idx_sh[rg * 8 + r] = fi;
        outf[QOFF + (size_t)(n0 + rg * 8 + r) * NQ + q] = (float)fi;
      }
    }
    __syncthreads();

    {
      const int r = tid & 31, db = tid >> 5;
      const float* crow = cbq + (size_t)idx_sh[r] * ND;
      float ls = 0.f;
      #pragma unroll
      for (int s = 0; s < 64; ++s) {
        int d = db * 64 + s;
        float cv = crow[d];
        float nv = resT[d][r] - cv;
        resT[d][r] = nv;
        qacc[s] += cv;
        ls += nv * nv;
      }
      #pragma unroll
      for (int m = 1; m < 64; m <<= 1) ls += __shfl_xor(ls, m, 64);
      if (lane == 0) wred[wv] = ls;
    }
    __syncthreads();
    if (tid == 0) lossws[blockIdx.x * NQ + q] = wred[0] + wred[1] + wred[2] + wred[3];
    __syncthreads();
  }

  {
    const int r = tid & 31, db = tid >> 5;
    #pragma unroll
    for (int g = 0; g < 16; ++g) {
      float4 w2;
      w2.x = qacc[g*4+0]; w2.y = qacc[g*4+1]; w2.z = qacc[g*4+2]; w2.w = qacc[g*4+3];
      *reinterpret_cast<float4*>(outf + (size_t)(n0 + r) * ND + db * 64 + g * 4) = w2;
    }
  }
}

__global__ __launch_bounds__(256) void loss_kernel(const float* __restrict__ lossws,
                                                   int n, float* __restrict__ outf) {
  __shared__ float red[256];
  const int tid = threadIdx.x;
  float s = 0.f;
  for (int i = tid; i < n; i += 256) s += lossws[i];
  red[tid] = s;
  __syncthreads();
  for (int w = 128; w > 0; w >>= 1) {
    if (tid < w) red[tid] += red[tid + w];
    __syncthreads();
  }
  if (tid == 0) outf[QOFF + (size_t)NROWTOT * NQ] = red[0] / 16777216.0f;
}

extern "C" void kernel_launch(void* const* d_in, const int* in_sizes, int n_in,
                              void* d_out, int out_size, void* d_ws, size_t ws_size,
                              hipStream_t stream) {
  (void)in_sizes; (void)n_in; (void)out_size;
  const float* emb = (const float*)d_in[0];
  const float* cbg = (const float*)d_in[1];
  float* wsf = (float*)d_ws;
  float* outf = (float*)d_out;

  cbsq_kernel<<<256, 256, 0, stream>>>(cbg, wsf);

  if (ws_size >= (size_t)18 * 1024 * 1024) {
    unsigned short* Bh = (unsigned short*)((char*)d_ws + 65536);
    unsigned short* Bl = Bh + 4194304;
    fmt_kernel<<<2048, 256, 0, stream>>>(cbg, Bh, Bl);
    rvq_mfma<<<1024, 512, 0, stream>>>(emb, cbg, wsf, wsf + 8192, Bh, Bl, outf);
    loss_kernel<<<1, 256, 0, stream>>>(wsf + 8192, 8192, outf);
  } else {
    rvq_fb<<<1024, 256, 0, stream>>>(emb, cbg, wsf, wsf + 8192, outf);
    loss_kernel<<<1, 256, 0, stream>>>(wsf + 8192, 8192, outf);
  }
}

// Round 11
// 3906.805 us; speedup vs baseline: 1.4433x; 1.4433x over previous
//
#include <hip/hip_runtime.h>
#include <hip/hip_bf16.h>

#define NQ 8
#define NC 1024
#define ND 512
#define NROWTOT 32768
#define QOFF 16777216ULL

typedef short short8 __attribute__((ext_vector_type(8)));
typedef float f32x16 __attribute__((ext_vector_type(16)));

__device__ __forceinline__ unsigned f2bf_u(float f) {
  unsigned u = __float_as_uint(f);
  return (u + 0x7FFFu + ((u >> 16) & 1u)) >> 16;
}
__device__ __forceinline__ void merge_in(float &d1, int &i1, float &d2, int &i2,
                                         float nd, int ni) {
  bool b1 = (nd < d1) || (nd == d1 && ni < i1);
  bool b2 = (nd < d2) || (nd == d2 && ni < i2);
  if (b1) { d2 = d1; i2 = i1; d1 = nd; i1 = ni; }
  else if (b2) { d2 = nd; i2 = ni; }
}

__global__ __launch_bounds__(256) void cbsq_kernel(const float* __restrict__ cbg,
                                                   float* __restrict__ ws) {
  const int tid = threadIdx.x, wv = tid >> 6, lane = tid & 63;
  const int cbase = blockIdx.x * 32 + wv * 8;
  for (int j = 0; j < 8; ++j) {
    const int c = cbase + j;
    const float4* p = reinterpret_cast<const float4*>(cbg + (size_t)c * ND + lane * 8);
    float4 a = p[0], b = p[1];
    float s = a.x*a.x + a.y*a.y + a.z*a.z + a.w*a.w
            + b.x*b.x + b.y*b.y + b.z*b.z + b.w*b.w;
    #pragma unroll
    for (int m = 1; m < 64; m <<= 1) s += __shfl_xor(s, m, 64);
    if (lane == 0) ws[c] = s;
  }
}

// Split codebooks into MFMA-B-frag-ordered bf16 hi/lo.
// chunk = (q*2+cp)*32+ks ; within chunk: [phys16][8k] bf16,
// i16 = grp*512 + col (grp = k-half of kstep), phys16 = i16 ^ ((i16>>3)&7)
__global__ __launch_bounds__(256) void fmt_kernel(const float* __restrict__ cbg,
                                                  unsigned short* __restrict__ Bh,
                                                  unsigned short* __restrict__ Bl) {
  int t = blockIdx.x * 256 + threadIdx.x;   // 524288 total
  int i16 = t & 1023, ks = (t >> 10) & 31, cp = (t >> 15) & 1, q = (t >> 16) & 7;
  int grp = i16 >> 9, col = i16 & 511, c = cp * 512 + col;
  const float* src = cbg + ((size_t)q * NC + c) * ND + ks * 16 + grp * 8;
  float4 a = reinterpret_cast<const float4*>(src)[0];
  float4 b = reinterpret_cast<const float4*>(src)[1];
  float v[8] = {a.x, a.y, a.z, a.w, b.x, b.y, b.z, b.w};
  unsigned short hv[8], lv[8];
  #pragma unroll
  for (int j = 0; j < 8; ++j) {
    unsigned hb = f2bf_u(v[j]);
    float hf = __uint_as_float(hb << 16);
    unsigned lb = f2bf_u(v[j] - hf);
    hv[j] = (unsigned short)hb; lv[j] = (unsigned short)lb;
  }
  int phys = i16 ^ ((i16 >> 3) & 7);
  size_t dst = (size_t)(t >> 10) * 8192 + (size_t)phys * 8;
  uint4 wh, wl;
  wh.x = hv[0] | ((unsigned)hv[1] << 16); wh.y = hv[2] | ((unsigned)hv[3] << 16);
  wh.z = hv[4] | ((unsigned)hv[5] << 16); wh.w = hv[6] | ((unsigned)hv[7] << 16);
  wl.x = lv[0] | ((unsigned)lv[1] << 16); wl.y = lv[2] | ((unsigned)lv[3] << 16);
  wl.z = lv[4] | ((unsigned)lv[5] << 16); wl.w = lv[6] | ((unsigned)lv[7] << 16);
  *reinterpret_cast<uint4*>(Bh + dst) = wh;
  *reinterpret_cast<uint4*>(Bl + dst) = wl;
}

#define ROWS64 64
#define RSTRIDE 260
#define TAU2 0.02f

// 1024 threads = 16 waves: 2 rowgroups x 8 colgroups (64 cols each).
// LOCKSTEP chunk walk: all blocks read the same 32 KB chunk per k-step ->
// per-XCD L2 fetches each chunk once from L3, serves 32 CUs; 2nd rowgroup
// re-read hits L1 (chunk == L1 size). waves_per_eu(4,4) pins VGPR cap at 128
// so the 2-deep fA/fB prefetch stays live (r8/r9 collapsed to 64 + spill).
__global__ __launch_bounds__(1024) __attribute__((amdgpu_waves_per_eu(4, 4)))
void rvq_mfma(
    const float* __restrict__ emb, const float* __restrict__ cbg,
    const float* __restrict__ cbsq_g, float* __restrict__ lossws,
    const unsigned short* __restrict__ Bh, const unsigned short* __restrict__ Bl,
    float* __restrict__ outf) {
  __shared__ unsigned resH[ROWS64 * RSTRIDE];   // 66560 B
  __shared__ unsigned resL[ROWS64 * RSTRIDE];   // 66560 B
  __shared__ float mrgd[2][8][ROWS64][2];       // 8 KB
  __shared__ int   mrgi[2][8][ROWS64][2];       // 8 KB
  __shared__ int   idx_all[NQ][ROWS64];
  __shared__ int   fi_sh[ROWS64];
  __shared__ int   tlist[ROWS64][3];
  __shared__ int   tcount;
  __shared__ float wred[16];

  const int tid = threadIdx.x;
  const int w = tid >> 6, l = tid & 63;
  const int n0 = blockIdx.x * ROWS64;
  const int rowbase = (w >> 3) * 32;          // 2 rowgroups
  const int colq = (w & 7) * 64;              // 8 colgroups of 64 cols
  const int arow = rowbase + (l & 31);

  union U8 { uint4 q4; short8 s; };

  const int row = tid & 63, kb0i = (tid >> 6) * 16;   // init/update mapping

  { // init: emb -> hi/lo bf16x2 packed, MFMA-operand order
    const float4* src = reinterpret_cast<const float4*>(emb + (size_t)(n0 + row) * ND + kb0i * 2);
    float4 v8[8];
    #pragma unroll
    for (int i = 0; i < 8; ++i) v8[i] = src[i];
    #pragma unroll
    for (int j = 0; j < 4; ++j) {
      float vv[8];
      vv[0]=v8[2*j].x; vv[1]=v8[2*j].y; vv[2]=v8[2*j].z; vv[3]=v8[2*j].w;
      vv[4]=v8[2*j+1].x; vv[5]=v8[2*j+1].y; vv[6]=v8[2*j+1].z; vv[7]=v8[2*j+1].w;
      unsigned hh[8], ll[8];
      #pragma unroll
      for (int e = 0; e < 8; ++e) {
        hh[e] = f2bf_u(vv[e]);
        ll[e] = f2bf_u(vv[e] - __uint_as_float(hh[e] << 16));
      }
      uint4 H, L;
      H.x = hh[0] | (hh[1] << 16); H.y = hh[2] | (hh[3] << 16);
      H.z = hh[4] | (hh[5] << 16); H.w = hh[6] | (hh[7] << 16);
      L.x = ll[0] | (ll[1] << 16); L.y = ll[2] | (ll[3] << 16);
      L.z = ll[4] | (ll[5] << 16); L.w = ll[6] | (ll[7] << 16);
      const int off = row * RSTRIDE + kb0i + 4 * j;
      *reinterpret_cast<uint4*>(&resH[off]) = H;
      *reinterpret_cast<uint4*>(&resL[off]) = L;
    }
  }

  int baddr[2];   // short offsets into a chunk, per tile
  #pragma unroll
  for (int t = 0; t < 2; ++t) {
    int i16 = ((l >> 5) << 9) + colq + t * 32 + (l & 31);
    baddr[t] = (i16 ^ ((i16 >> 3) & 7)) * 8;
  }
  const int kbh = (l >> 5) * 4;          // khalf kb offset
  const int abase = arow * RSTRIDE;
  __syncthreads();

  for (int q = 0; q < NQ; ++q) {
    if (tid == 0) tcount = 0;   // ordered before merge-phase atomics by the post-GEMM barrier

    #pragma unroll 1
    for (int cp = 0; cp < 2; ++cp) {
      f32x16 acc[2];
      #pragma unroll
      for (int t = 0; t < 2; ++t)
        #pragma unroll
        for (int e = 0; e < 16; ++e) acc[t][e] = 0.f;

      const unsigned short* bhc = Bh + (size_t)((q * 2 + cp) * 32) * 8192;
      const unsigned short* blc = Bl + (size_t)((q * 2 + cp) * 32) * 8192;
      uint4 fA[4], fB[4];
      uint4 aAh, aAl, aBh, aBl;

      // hoist sq^2 loads: latency hidden under the whole GEMM
      float sqv[2];
      #pragma unroll
      for (int t = 0; t < 2; ++t)
        sqv[t] = cbsq_g[q * NC + cp * 512 + colq + t * 32 + (l & 31)];

#define KS(i) ((i) & 31)

#define LOADB(buf, kk) { \
      const unsigned short* _h = bhc + (size_t)(kk) * 8192; \
      const unsigned short* _l = blc + (size_t)(kk) * 8192; \
      buf[0] = *reinterpret_cast<const uint4*>(_h + baddr[0]); \
      buf[1] = *reinterpret_cast<const uint4*>(_h + baddr[1]); \
      buf[2] = *reinterpret_cast<const uint4*>(_l + baddr[0]); \
      buf[3] = *reinterpret_cast<const uint4*>(_l + baddr[1]); }

#define READA(ah_, al_, kk) { \
      const int _a = abase + (kk) * 8 + kbh; \
      ah_ = *reinterpret_cast<const uint4*>(&resH[_a]); \
      al_ = *reinterpret_cast<const uint4*>(&resL[_a]); }

#define MFMAS(ah_, al_, buf) { \
      U8 A1, A2; A1.q4 = ah_; A2.q4 = al_; \
      _Pragma("unroll") \
      for (int t = 0; t < 2; ++t) { \
        U8 bh_, bl_; bh_.q4 = buf[t]; bl_.q4 = buf[2 + t]; \
        acc[t] = __builtin_amdgcn_mfma_f32_32x32x16_bf16(A1.s, bh_.s, acc[t], 0, 0, 0); \
        acc[t] = __builtin_amdgcn_mfma_f32_32x32x16_bf16(A2.s, bh_.s, acc[t], 0, 0, 0); \
        acc[t] = __builtin_amdgcn_mfma_f32_32x32x16_bf16(A1.s, bl_.s, acc[t], 0, 0, 0); \
      } }

      LOADB(fA, KS(0)); LOADB(fB, KS(1)); READA(aAh, aAl, KS(0));
      #pragma unroll 1
      for (int ks = 0; ks < 32; ks += 2) {
        READA(aBh, aBl, KS(ks + 1));
        MFMAS(aAh, aAl, fA);
        LOADB(fA, KS(ks + 2));          // 2-deep refill (wraps harmlessly at end)
        READA(aAh, aAl, KS(ks + 2));
        MFMAS(aBh, aBl, fB);
        LOADB(fB, KS(ks + 3));          // wraps harmlessly at end
      }
#undef LOADB
#undef READA
#undef MFMAS
#undef KS

      // epilogue: per-row top-2 across this wave's 64 cols
      #pragma unroll
      for (int rg2 = 0; rg2 < 16; ++rg2) {
        float d1 = INFINITY, d2 = INFINITY; int i1 = 0x7fffffff, i2 = 0x7fffffff;
        #pragma unroll
        for (int t = 0; t < 2; ++t) {
          int col = cp * 512 + colq + t * 32 + (l & 31);
          float dd = sqv[t] - 2.0f * acc[t][rg2];
          merge_in(d1, i1, d2, i2, dd, col);
        }
        #pragma unroll
        for (int m = 1; m < 32; m <<= 1) {
          float od1 = __shfl_xor(d1, m, 64), od2 = __shfl_xor(d2, m, 64);
          int oi1 = __shfl_xor(i1, m, 64), oi2 = __shfl_xor(i2, m, 64);
          merge_in(d1, i1, d2, i2, od1, oi1);
          merge_in(d1, i1, d2, i2, od2, oi2);
        }
        if ((l & 31) == 0) {
          int h = l >> 5;
          int rr = rowbase + (rg2 & 3) + 8 * (rg2 >> 2) + 4 * h;
          mrgd[cp][w & 7][rr][0] = d1; mrgd[cp][w & 7][rr][1] = d2;
          mrgi[cp][w & 7][rr][0] = i1; mrgi[cp][w & 7][rr][1] = i2;
        }
      }
    }
    __syncthreads();

    // per-row merge of 2cp x 8 colgroups x top2 + trigger list
    if (tid < ROWS64) {
      float d1 = INFINITY, d2 = INFINITY; int i1 = 0x7fffffff, i2 = 0x7fffffff;
      #pragma unroll
      for (int c2 = 0; c2 < 2; ++c2)
        #pragma unroll
        for (int s2 = 0; s2 < 8; ++s2) {
          merge_in(d1, i1, d2, i2, mrgd[c2][s2][tid][0], mrgi[c2][s2][tid][0]);
          merge_in(d1, i1, d2, i2, mrgd[c2][s2][tid][1], mrgi[c2][s2][tid][1]);
        }
      int fi = i1 < 0 ? 0 : (i1 > NC - 1 ? NC - 1 : i1);
      int ib = i2 < 0 ? 0 : (i2 > NC - 1 ? NC - 1 : i2);
      fi_sh[tid] = fi;
      if (d2 - d1 < TAU2 && ib != fi) {
        int p = atomicAdd(&tcount, 1);
        tlist[p][0] = tid; tlist[p][1] = fi; tlist[p][2] = ib;
      }
    }
    __syncthreads();

    // cooperative exact rescore (stepped-fp32 residual, fp64 dists)
    {
      int nt_ = tcount;
      for (int it = w; it < nt_; it += 16) {
        int rr = tlist[it][0], ia = tlist[it][1], ib = tlist[it][2];
        float rv[8];
        const float4* ep = reinterpret_cast<const float4*>(emb + (size_t)(n0 + rr) * ND + l * 8);
        float4 e0 = ep[0], e1 = ep[1];
        rv[0]=e0.x; rv[1]=e0.y; rv[2]=e0.z; rv[3]=e0.w;
        rv[4]=e1.x; rv[5]=e1.y; rv[6]=e1.z; rv[7]=e1.w;
        for (int t2 = 0; t2 < q; ++t2) {
          const float4* cr = reinterpret_cast<const float4*>(
              cbg + ((size_t)t2 * NC + idx_all[t2][rr]) * ND + l * 8);
          float4 c0 = cr[0], c1 = cr[1];
          rv[0]-=c0.x; rv[1]-=c0.y; rv[2]-=c0.z; rv[3]-=c0.w;
          rv[4]-=c1.x; rv[5]-=c1.y; rv[6]-=c1.z; rv[7]-=c1.w;
        }
        double da = 0.0, db = 0.0;
        {
          const float4* cr = reinterpret_cast<const float4*>(
              cbg + ((size_t)q * NC + ia) * ND + l * 8);
          float4 c0 = cr[0], c1 = cr[1];
          float cv[8] = {c0.x,c0.y,c0.z,c0.w,c1.x,c1.y,c1.z,c1.w};
          #pragma unroll
          for (int j = 0; j < 8; ++j) { double e = (double)cv[j] - (double)rv[j]; da += e * e; }
        }
        {
          const float4* cr = reinterpret_cast<const float4*>(
              cbg + ((size_t)q * NC + ib) * ND + l * 8);
          float4 c0 = cr[0], c1 = cr[1];
          float cv[8] = {c0.x,c0.y,c0.z,c0.w,c1.x,c1.y,c1.z,c1.w};
          #pragma unroll
          for (int j = 0; j < 8; ++j) { double e = (double)cv[j] - (double)rv[j]; db += e * e; }
        }
        #pragma unroll
        for (int m = 1; m < 64; m <<= 1) { da += __shfl_xor(da, m, 64); db += __shfl_xor(db, m, 64); }
        if (l == 0 && (db < da || (db == da && ib < ia))) fi_sh[rr] = ib;
      }
    }
    __syncthreads();

    if (tid < ROWS64) {
      idx_all[q][tid] = fi_sh[tid];
      outf[QOFF + (size_t)(n0 + tid) * NQ + q] = (float)fi_sh[tid];
    }

    // residual update + loss (+ fused quantized at last stage); 16 threads/row
    {
      const float* crow = cbg + ((size_t)q * NC + fi_sh[row]) * ND;
      const float4* cp4 = reinterpret_cast<const float4*>(crow + kb0i * 2);
      const float4* ep4 = reinterpret_cast<const float4*>(emb + (size_t)(n0 + row) * ND + kb0i * 2);
      float4* op4 = reinterpret_cast<float4*>(outf + (size_t)(n0 + row) * ND + kb0i * 2);
      float4 cv8[8];
      #pragma unroll
      for (int u2 = 0; u2 < 8; ++u2) cv8[u2] = cp4[u2];
      float ls = 0.f;
      #pragma unroll
      for (int j = 0; j < 4; ++j) {
        const int off = row * RSTRIDE + kb0i + 4 * j;
        uint4 H = *reinterpret_cast<const uint4*>(&resH[off]);
        uint4 L = *reinterpret_cast<const uint4*>(&resL[off]);
        unsigned hu[4] = {H.x, H.y, H.z, H.w};
        unsigned lu[4] = {L.x, L.y, L.z, L.w};
        float cf[8];
        cf[0]=cv8[2*j].x; cf[1]=cv8[2*j].y; cf[2]=cv8[2*j].z; cf[3]=cv8[2*j].w;
        cf[4]=cv8[2*j+1].x; cf[5]=cv8[2*j+1].y; cf[6]=cv8[2*j+1].z; cf[7]=cv8[2*j+1].w;
        float x[8];
        #pragma unroll
        for (int e = 0; e < 4; ++e) {
          float rlo = __uint_as_float(hu[e] << 16) + __uint_as_float(lu[e] << 16);
          float rhi = __uint_as_float(hu[e] & 0xFFFF0000u) + __uint_as_float(lu[e] & 0xFFFF0000u);
          x[2*e]   = rlo - cf[2*e];
          x[2*e+1] = rhi - cf[2*e+1];
        }
        unsigned nh[4], nl[4];
        #pragma unroll
        for (int e = 0; e < 4; ++e) {
          unsigned h0 = f2bf_u(x[2*e]);
          unsigned l0 = f2bf_u(x[2*e] - __uint_as_float(h0 << 16));
          unsigned h1 = f2bf_u(x[2*e+1]);
          unsigned l1 = f2bf_u(x[2*e+1] - __uint_as_float(h1 << 16));
          nh[e] = h0 | (h1 << 16);
          nl[e] = l0 | (l1 << 16);
          ls += x[2*e] * x[2*e] + x[2*e+1] * x[2*e+1];
        }
        uint4 NH, NL;
        NH.x = nh[0]; NH.y = nh[1]; NH.z = nh[2]; NH.w = nh[3];
        NL.x = nl[0]; NL.y = nl[1]; NL.z = nl[2]; NL.w = nl[3];
        *reinterpret_cast<uint4*>(&resH[off]) = NH;
        *reinterpret_cast<uint4*>(&resL[off]) = NL;
        if (q == NQ - 1) {
          float4 e0 = ep4[2*j], e1 = ep4[2*j+1];
          float4 q0, q1;
          q0.x = e0.x - x[0]; q0.y = e0.y - x[1]; q0.z = e0.z - x[2]; q0.w = e0.w - x[3];
          q1.x = e1.x - x[4]; q1.y = e1.y - x[5]; q1.z = e1.z - x[6]; q1.w = e1.w - x[7];
          op4[2*j] = q0; op4[2*j+1] = q1;
        }
      }
      #pragma unroll
      for (int m = 1; m < 64; m <<= 1) ls += __shfl_xor(ls, m, 64);
      if (l == 0) wred[w] = ls;
    }
    __syncthreads();
    if (tid == 0) {
      float s = 0.f;
      #pragma unroll
      for (int i = 0; i < 16; ++i) s += wred[i];
      lossws[blockIdx.x * NQ + q] = s;
    }
    __syncthreads();
  }
}

// ---------------- fallback (round-4 passing kernel) ----------------
#define ROWS 32
#define BK 32
#define CP 512
#define TAU 0.05f

__global__ __launch_bounds__(256, 1) void rvq_fb(
    const float* __restrict__ emb, const float* __restrict__ cbg,
    const float* __restrict__ cbsq, float* __restrict__ lossws,
    float* __restrict__ outf) {
  __shared__ float resT[ND][ROWS];
  __shared__ float cc[BK][CP];
  __shared__ int   idx_sh[ROWS];
  __shared__ float wred[4];

  const int tid = threadIdx.x;
  const int wv = tid >> 6, lane = tid & 63;
  const int rg = wv, cg = lane;
  const int n0 = blockIdx.x * ROWS;

  float qacc[64];
  #pragma unroll
  for (int s = 0; s < 64; ++s) qacc[s] = 0.f;

  {
    const int r = tid & 31, db = tid >> 5;
    const float4* src = reinterpret_cast<const float4*>(emb + (size_t)(n0 + r) * ND + db * 64);
    #pragma unroll
    for (int s = 0; s < 16; ++s) {
      float4 v = src[s];
      int d = db * 64 + s * 4;
      resT[d+0][r] = v.x; resT[d+1][r] = v.y; resT[d+2][r] = v.z; resT[d+3][r] = v.w;
    }
  }
  __syncthreads();

  const int c0l = cg * 8;
  const int swm = (c0l >> 6) << 2;
  const int off0 = c0l ^ swm;
  const int off1 = (c0l + 4) ^ swm;

  for (int q = 0; q < NQ; ++q) {
    const float* cbq = cbg + (size_t)q * NC * ND;
    float bd1[8], bd2[8]; int bi1[8], bi2[8];
    #pragma unroll
    for (int j = 0; j < 8; ++j) { bd1[j]=INFINITY; bd2[j]=INFINITY; bi1[j]=0x7fffffff; bi2[j]=0x7fffffff; }

    for (int cp = 0; cp < 2; ++cp) {
      float acc[8][8];
      #pragma unroll
      for (int a = 0; a < 8; ++a)
        #pragma unroll
        for (int b = 0; b < 8; ++b) acc[a][b] = 0.f;

      for (int kc = 0; kc < ND / BK; ++kc) {
        __syncthreads();
        {
          const int half = tid & 1;
          const int k0 = half * 16;
          #pragma unroll
          for (int it = 0; it < 4; ++it) {
            const int c = (tid >> 1) + it * 128;
            const int pc = c ^ ((c >> 6) << 2);
            const float4* src = reinterpret_cast<const float4*>(
                cbq + (size_t)(cp * CP + c) * ND + kc * BK + half * 16);
            float4 v0 = src[0], v1 = src[1], v2 = src[2], v3 = src[3];
            cc[k0+ 0][pc]=v0.x; cc[k0+ 1][pc]=v0.y; cc[k0+ 2][pc]=v0.z; cc[k0+ 3][pc]=v0.w;
            cc[k0+ 4][pc]=v1.x; cc[k0+ 5][pc]=v1.y; cc[k0+ 6][pc]=v1.z; cc[k0+ 7][pc]=v1.w;
            cc[k0+ 8][pc]=v2.x; cc[k0+ 9][pc]=v2.y; cc[k0+10][pc]=v2.z; cc[k0+11][pc]=v2.w;
            cc[k0+12][pc]=v3.x; cc[k0+13][pc]=v3.y; cc[k0+14][pc]=v3.z; cc[k0+15][pc]=v3.w;
          }
        }
        __syncthreads();

        float tmp[8][8];
        #pragma unroll
        for (int a = 0; a < 8; ++a)
          #pragma unroll
          for (int b = 0; b < 8; ++b) tmp[a][b] = 0.f;

        #pragma unroll
        for (int kk = 0; kk < BK; ++kk) {
          const float4* rp = reinterpret_cast<const float4*>(&resT[kc * BK + kk][rg * 8]);
          float4 r0 = rp[0], r1 = rp[1];
          const float* ccrow = &cc[kk][0];
          float4 c0 = *reinterpret_cast<const float4*>(ccrow + off0);
          float4 c1 = *reinterpret_cast<const float4*>(ccrow + off1);
          float rv[8] = {r0.x, r0.y, r0.z, r0.w, r1.x, r1.y, r1.z, r1.w};
          float cv[8] = {c0.x, c0.y, c0.z, c0.w, c1.x, c1.y, c1.z, c1.w};
          #pragma unroll
          for (int a = 0; a < 8; ++a)
            #pragma unroll
            for (int b = 0; b < 8; ++b)
              tmp[a][b] = fmaf(rv[a], cv[b], tmp[a][b]);
        }
        #pragma unroll
        for (int a = 0; a < 8; ++a)
          #pragma unroll
          for (int b = 0; b < 8; ++b) acc[a][b] += tmp[a][b];
      }

      const float4* qp = reinterpret_cast<const float4*>(cbsq + q * NC + cp * CP + cg * 8);
      float4 s0 = qp[0], s1 = qp[1];
      float sqv[8] = {s0.x, s0.y, s0.z, s0.w, s1.x, s1.y, s1.z, s1.w};
      #pragma unroll
      for (int r = 0; r < 8; ++r) {
        float d1 = INFINITY, d2 = INFINITY; int i1 = 0x7fffffff, i2 = 0x7fffffff;
        #pragma unroll
        for (int j = 0; j < 8; ++j) {
          float dd = sqv[j] - 2.0f * acc[r][j];
          merge_in(d1, i1, d2, i2, dd, cp * CP + cg * 8 + j);
        }
        #pragma unroll
        for (int m = 1; m < 64; m <<= 1) {
          float od1 = __shfl_xor(d1, m, 64), od2 = __shfl_xor(d2, m, 64);
          int oi1 = __shfl_xor(i1, m, 64), oi2 = __shfl_xor(i2, m, 64);
          merge_in(d1, i1, d2, i2, od1, oi1);
          merge_in(d1, i1, d2, i2, od2, oi2);
        }
        merge_in(bd1[r], bi1[r], bd2[r], bi2[r], d1, i1);
        merge_in(bd1[r], bi1[r], bd2[r], bi2[r], d2, i2);
      }
    }

    #pragma unroll 1
    for (int r = 0; r < 8; ++r) {
      int fi = bi1[r];
      if (bd2[r] - bd1[r] < TAU) {
        const int row = rg * 8 + r;
        const int ia = bi1[r], ib = bi2[r];
        double da = 0.0, db2 = 0.0;
        #pragma unroll 1
        for (int t = 0; t < 2; ++t) {
          const int cidx = t ? ib : ia;
          const float* cr = cbq + (size_t)cidx * ND;
          double dot = 0.0, ss = 0.0;
          #pragma unroll
          for (int u = 0; u < 8; ++u) {
            int k = lane * 8 + u;
            double cvv = (double)cr[k];
            double rvv = (double)resT[k][row];
            dot += cvv * rvv; ss += cvv * cvv;
          }
          #pragma unroll
          for (int m = 1; m < 64; m <<= 1) { dot += __shfl_xor(dot, m, 64); ss += __shfl_xor(ss, m, 64); }
          double dd = ss - 2.0 * dot;
          if (t) db2 = dd; else da = dd;
        }
        if (db2 < da || (db2 == da && ib < ia)) fi = ib;
      }
      fi = fi < 0 ? 0 : (fi > NC - 1 ? NC - 1 : fi);
      if (lane == 0) {
        idx_sh[rg * 8 + r] = fi;
        outf[QOFF + (size_t)(n0 + rg * 8 + r) * NQ + q] = (float)fi;
      }
    }
    __syncthreads();

    {
      const int r = tid & 31, db = tid >> 5;
      const float* crow = cbq + (size_t)idx_sh[r] * ND;
      float ls = 0.f;
      #pragma unroll
      for (int s = 0; s < 64; ++s) {
        int d = db * 64 + s;
        float cv = crow[d];
        float nv = resT[d][r] - cv;
        resT[d][r] = nv;
        qacc[s] += cv;
        ls += nv * nv;
      }
      #pragma unroll
      for (int m = 1; m < 64; m <<= 1) ls += __shfl_xor(ls, m, 64);
      if (lane == 0) wred[wv] = ls;
    }
    __syncthreads();
    if (tid == 0) lossws[blockIdx.x * NQ + q] = wred[0] + wred[1] + wred[2] + wred[3];
    __syncthreads();
  }

  {
    const int r = tid & 31, db = tid >> 5;
    #pragma unroll
    for (int g = 0; g < 16; ++g) {
      float4 w2;
      w2.x = qacc[g*4+0]; w2.y = qacc[g*4+1]; w2.z = qacc[g*4+2]; w2.w = qacc[g*4+3];
      *reinterpret_cast<float4*>(outf + (size_t)(n0 + r) * ND + db * 64 + g * 4) = w2;
    }
  }
}

__global__ __launch_bounds__(256) void loss_kernel(const float* __restrict__ lossws,
                                                   int n, float* __restrict__ outf) {
  __shared__ float red[256];
  const int tid = threadIdx.x;
  float s = 0.f;
  for (int i = tid; i < n; i += 256) s += lossws[i];
  red[tid] = s;
  __syncthreads();
  for (int w = 128; w > 0; w >>= 1) {
    if (tid < w) red[tid] += red[tid + w];
    __syncthreads();
  }
  if (tid == 0) outf[QOFF + (size_t)NROWTOT * NQ] = red[0] / 16777216.0f;
}

extern "C" void kernel_launch(void* const* d_in, const int* in_sizes, int n_in,
                              void* d_out, int out_size, void* d_ws, size_t ws_size,
                              hipStream_t stream) {
  (void)in_sizes; (void)n_in; (void)out_size;
  const float* emb = (const float*)d_in[0];
  const float* cbg = (const float*)d_in[1];
  float* wsf = (float*)d_ws;
  float* outf = (float*)d_out;

  cbsq_kernel<<<256, 256, 0, stream>>>(cbg, wsf);

  if (ws_size >= (size_t)18 * 1024 * 1024) {
    unsigned short* Bh = (unsigned short*)((char*)d_ws + 65536);
    unsigned short* Bl = Bh + 4194304;
    fmt_kernel<<<2048, 256, 0, stream>>>(cbg, Bh, Bl);
    rvq_mfma<<<512, 1024, 0, stream>>>(emb, cbg, wsf, wsf + 8192, Bh, Bl, outf);
    loss_kernel<<<1, 256, 0, stream>>>(wsf + 8192, 4096, outf);
  } else {
    rvq_fb<<<1024, 256, 0, stream>>>(emb, cbg, wsf, wsf + 8192, outf);
    loss_kernel<<<1, 256, 0, stream>>>(wsf + 8192, 8192, outf);
  }
}